// Round 1
// baseline (3689.016 us; speedup 1.0000x reference)
//
#include <hip/hip_runtime.h>
#include <hip/hip_bf16.h>

#define NTOK 4096
#define HID 1024
#define EXP 4096
#define NE 8

typedef __attribute__((ext_vector_type(8))) short bf16x8;
typedef __attribute__((ext_vector_type(4))) float f32x4;

__device__ inline unsigned short f2bf(float f) {
    union { float f; unsigned int u; } v; v.f = f;
    unsigned int u = v.u;
    return (unsigned short)((u + 0x7FFFu + ((u >> 16) & 1u)) >> 16);
}

// ---------------- gate: logits, softmax-top2, routing counts ----------------
__global__ void gate_kernel(const float* __restrict__ x, const float* __restrict__ gw,
                            int* __restrict__ topi, float* __restrict__ topw,
                            int* __restrict__ cnt) {
    int wave = threadIdx.x >> 6;
    int lane = threadIdx.x & 63;
    int t = blockIdx.x * 4 + wave;
    if (t >= NTOK) return;
    float acc[NE];
#pragma unroll
    for (int e = 0; e < NE; e++) acc[e] = 0.f;
    const float* xr = x + (size_t)t * HID;
    for (int i = lane; i < HID; i += 64) {
        float xv = xr[i];
#pragma unroll
        for (int e = 0; e < NE; e++) acc[e] += xv * gw[e * HID + i];
    }
#pragma unroll
    for (int e = 0; e < NE; e++) {
#pragma unroll
        for (int off = 32; off > 0; off >>= 1)
            acc[e] += __shfl_xor(acc[e], off);
    }
    if (lane == 0) {
        int i0 = 0; float m0 = acc[0];
#pragma unroll
        for (int e = 1; e < NE; e++) if (acc[e] > m0) { m0 = acc[e]; i0 = e; }
        int i1 = -1; float m1 = -1e30f;
#pragma unroll
        for (int e = 0; e < NE; e++) if (e != i0 && acc[e] > m1) { m1 = acc[e]; i1 = e; }
        float w0 = 1.f / (1.f + expf(m1 - m0));
        float w1 = 1.f - w0;
        topi[2 * t] = i0; topi[2 * t + 1] = i1;
        topw[2 * t] = w0; topw[2 * t + 1] = w1;
        atomicAdd(&cnt[i0], 1);
        atomicAdd(&cnt[i1], 1);
    }
}

__global__ void offset_kernel(const int* __restrict__ cnt, int* __restrict__ off,
                              int* __restrict__ cnt2) {
    if (threadIdx.x == 0) {
        int s = 0;
        for (int e = 0; e < NE; e++) { off[e] = s; s += cnt[e]; cnt2[e] = 0; }
    }
}

__global__ void fill_kernel(const int* __restrict__ topi, const float* __restrict__ topw,
                            const int* __restrict__ off, int* __restrict__ cnt2,
                            int* __restrict__ rowtok, float* __restrict__ rowwgt) {
    int t = blockIdx.x * blockDim.x + threadIdx.x;
    if (t >= NTOK) return;
#pragma unroll
    for (int k = 0; k < 2; k++) {
        int e = topi[2 * t + k];
        int pos = atomicAdd(&cnt2[e], 1);
        rowtok[off[e] + pos] = t;
        rowwgt[off[e] + pos] = topw[2 * t + k];
    }
}

// ---------------- GEMM1: H = silu(Xg @ W1^T) * (Xg @ W3^T), bf16 out ----------------
#define BM1 128
#define BN1 64
#define BK 64

__launch_bounds__(256, 2)
__global__ void gemm1_kernel(const float* __restrict__ x,
                             const float* __restrict__ w1,
                             const float* __restrict__ w3,
                             const int* __restrict__ rowtok,
                             const int* __restrict__ off,
                             const int* __restrict__ cnt,
                             unsigned short* __restrict__ Hbuf) {
    int e = blockIdx.z;
    int Me = cnt[e];
    int m_base = blockIdx.x * BM1;
    if (m_base >= Me) return;
    int off_e = off[e];
    int n_base = blockIdx.y * BN1;

    __shared__ __align__(16) unsigned short As[BM1 * BK];
    __shared__ __align__(16) unsigned short B1s[BN1 * BK];
    __shared__ __align__(16) unsigned short B3s[BN1 * BK];

    int tid = threadIdx.x;
    int lane = tid & 63;
    int wv = tid >> 6;
    int wr = wv >> 1, wc = wv & 1;

    int srow = tid >> 4;          // 0..15
    int scol4 = (tid & 15) * 4;   // float col

    int tokr[8];
#pragma unroll
    for (int p = 0; p < 8; p++) {
        int r = srow + p * 16;
        int gr = m_base + r;
        tokr[p] = (gr < Me) ? rowtok[off_e + gr] : -1;
    }

    const float* w1p = w1 + (size_t)e * EXP * HID;
    const float* w3p = w3 + (size_t)e * EXP * HID;

    f32x4 zero = {0.f, 0.f, 0.f, 0.f};
    f32x4 acc1[4][2], acc3[4][2];
#pragma unroll
    for (int i = 0; i < 4; i++)
#pragma unroll
        for (int j = 0; j < 2; j++) { acc1[i][j] = zero; acc3[i][j] = zero; }

    for (int kb = 0; kb < HID; kb += BK) {
        __syncthreads();
        // stage A (gathered x rows, fp32 -> bf16), 128 rows
#pragma unroll
        for (int p = 0; p < 8; p++) {
            int r = srow + p * 16;
            float4 vin = make_float4(0.f, 0.f, 0.f, 0.f);
            if (tokr[p] >= 0)
                vin = *reinterpret_cast<const float4*>(x + (size_t)tokr[p] * HID + kb + scol4);
            ushort4 o;
            o.x = f2bf(vin.x); o.y = f2bf(vin.y); o.z = f2bf(vin.z); o.w = f2bf(vin.w);
            int c = scol4 ^ ((r & 7) << 3);
            *reinterpret_cast<ushort4*>(&As[r * BK + c]) = o;
        }
        // stage W1 + W3 tiles (64 rows each)
#pragma unroll
        for (int p = 0; p < 4; p++) {
            int r = srow + p * 16;
            size_t gofs = (size_t)(n_base + r) * HID + kb + scol4;
            float4 v1 = *reinterpret_cast<const float4*>(w1p + gofs);
            float4 v3 = *reinterpret_cast<const float4*>(w3p + gofs);
            ushort4 o1, o3;
            o1.x = f2bf(v1.x); o1.y = f2bf(v1.y); o1.z = f2bf(v1.z); o1.w = f2bf(v1.w);
            o3.x = f2bf(v3.x); o3.y = f2bf(v3.y); o3.z = f2bf(v3.z); o3.w = f2bf(v3.w);
            int c = scol4 ^ ((r & 7) << 3);
            *reinterpret_cast<ushort4*>(&B1s[r * BK + c]) = o1;
            *reinterpret_cast<ushort4*>(&B3s[r * BK + c]) = o3;
        }
        __syncthreads();
        // compute
#pragma unroll
        for (int kk = 0; kk < BK; kk += 32) {
            int fc = kk + 8 * (lane >> 4);
            bf16x8 a[4], b1[2], b3[2];
#pragma unroll
            for (int mr = 0; mr < 4; mr++) {
                int r = wr * 64 + mr * 16 + (lane & 15);
                a[mr] = *reinterpret_cast<const bf16x8*>(&As[r * BK + (fc ^ ((r & 7) << 3))]);
            }
#pragma unroll
            for (int nr = 0; nr < 2; nr++) {
                int r = wc * 32 + nr * 16 + (lane & 15);
                int cc = fc ^ ((r & 7) << 3);
                b1[nr] = *reinterpret_cast<const bf16x8*>(&B1s[r * BK + cc]);
                b3[nr] = *reinterpret_cast<const bf16x8*>(&B3s[r * BK + cc]);
            }
#pragma unroll
            for (int mr = 0; mr < 4; mr++)
#pragma unroll
                for (int nr = 0; nr < 2; nr++) {
                    acc1[mr][nr] = __builtin_amdgcn_mfma_f32_16x16x32_bf16(a[mr], b1[nr], acc1[mr][nr], 0, 0, 0);
                    acc3[mr][nr] = __builtin_amdgcn_mfma_f32_16x16x32_bf16(a[mr], b3[nr], acc3[mr][nr], 0, 0, 0);
                }
        }
    }
    // epilogue: silu(c1)*c3 -> bf16 H
#pragma unroll
    for (int mr = 0; mr < 4; mr++) {
#pragma unroll
        for (int rg = 0; rg < 4; rg++) {
            int rl = wr * 64 + mr * 16 + (lane >> 4) * 4 + rg;
            int gr = m_base + rl;
            if (gr >= Me) continue;
            size_t hrow = (size_t)(off_e + gr) * EXP;
#pragma unroll
            for (int nr = 0; nr < 2; nr++) {
                float u = acc1[mr][nr][rg];
                float v = acc3[mr][nr][rg];
                float h = (u / (1.f + expf(-u))) * v;
                int cl = n_base + wc * 32 + nr * 16 + (lane & 15);
                Hbuf[hrow + cl] = f2bf(h);
            }
        }
    }
}

// ---------------- GEMM2: out[tok] += wgt * (H @ W2^T) ----------------
#define BM2 128
#define BN2 128

__launch_bounds__(256, 2)
__global__ void gemm2_kernel(const unsigned short* __restrict__ Hbuf,
                             const float* __restrict__ w2,
                             const int* __restrict__ rowtok,
                             const float* __restrict__ rowwgt,
                             const int* __restrict__ off,
                             const int* __restrict__ cnt,
                             float* __restrict__ out) {
    int e = blockIdx.z;
    int Me = cnt[e];
    int m_base = blockIdx.x * BM2;
    if (m_base >= Me) return;
    int off_e = off[e];
    int n_base = blockIdx.y * BN2;

    __shared__ __align__(16) unsigned short As[BM2 * BK];
    __shared__ __align__(16) unsigned short Bs[BN2 * BK];

    int tid = threadIdx.x, lane = tid & 63, wv = tid >> 6;
    int wr = wv >> 1, wc = wv & 1;

    f32x4 zero = {0.f, 0.f, 0.f, 0.f};
    f32x4 acc[4][4];
#pragma unroll
    for (int i = 0; i < 4; i++)
#pragma unroll
        for (int j = 0; j < 4; j++) acc[i][j] = zero;

    int arow = tid >> 3;            // 0..31
    int acol8 = (tid & 7) * 8;      // bf16 col
    int brow = tid >> 4;            // 0..15
    int bcol4 = (tid & 15) * 4;     // float col

    const float* w2p = w2 + (size_t)e * HID * EXP;

    for (int kb = 0; kb < EXP; kb += BK) {
        __syncthreads();
        // stage A (H rows, already bf16)
#pragma unroll
        for (int p = 0; p < 4; p++) {
            int r = arow + p * 32;
            long grow = (long)off_e + m_base + r;
            if (grow > 2L * NTOK - 1) grow = 2L * NTOK - 1;
            int4 vin = *reinterpret_cast<const int4*>(Hbuf + grow * EXP + kb + acol8);
            int c = acol8 ^ ((r & 7) << 3);
            *reinterpret_cast<int4*>(&As[r * BK + c]) = vin;
        }
        // stage B (w2 fp32 -> bf16), 128 rows
#pragma unroll
        for (int p = 0; p < 8; p++) {
            int r = brow + p * 16;
            float4 v = *reinterpret_cast<const float4*>(w2p + (size_t)(n_base + r) * EXP + kb + bcol4);
            ushort4 o;
            o.x = f2bf(v.x); o.y = f2bf(v.y); o.z = f2bf(v.z); o.w = f2bf(v.w);
            int c = bcol4 ^ ((r & 7) << 3);
            *reinterpret_cast<ushort4*>(&Bs[r * BK + c]) = o;
        }
        __syncthreads();
#pragma unroll
        for (int kk = 0; kk < BK; kk += 32) {
            int fc = kk + 8 * (lane >> 4);
            bf16x8 a[4], b[4];
#pragma unroll
            for (int mr = 0; mr < 4; mr++) {
                int r = wr * 64 + mr * 16 + (lane & 15);
                a[mr] = *reinterpret_cast<const bf16x8*>(&As[r * BK + (fc ^ ((r & 7) << 3))]);
            }
#pragma unroll
            for (int nr = 0; nr < 4; nr++) {
                int r = wc * 64 + nr * 16 + (lane & 15);
                b[nr] = *reinterpret_cast<const bf16x8*>(&Bs[r * BK + (fc ^ ((r & 7) << 3))]);
            }
#pragma unroll
            for (int mr = 0; mr < 4; mr++)
#pragma unroll
                for (int nr = 0; nr < 4; nr++)
                    acc[mr][nr] = __builtin_amdgcn_mfma_f32_16x16x32_bf16(a[mr], b[nr], acc[mr][nr], 0, 0, 0);
        }
    }
    // epilogue: scale by gate weight, atomic add into out
#pragma unroll
    for (int mr = 0; mr < 4; mr++) {
#pragma unroll
        for (int rg = 0; rg < 4; rg++) {
            int rl = wr * 64 + mr * 16 + (lane >> 4) * 4 + rg;
            int gr = m_base + rl;
            if (gr >= Me) continue;
            int tok = rowtok[off_e + gr];
            float wgt = rowwgt[off_e + gr];
#pragma unroll
            for (int nr = 0; nr < 4; nr++) {
                int cl = n_base + wc * 64 + nr * 16 + (lane & 15);
                atomicAdd(&out[(size_t)tok * HID + cl], acc[mr][nr][rg] * wgt);
            }
        }
    }
}

extern "C" void kernel_launch(void* const* d_in, const int* in_sizes, int n_in,
                              void* d_out, int out_size, void* d_ws, size_t ws_size,
                              hipStream_t stream) {
    const float* x  = (const float*)d_in[0];
    const float* gw = (const float*)d_in[1];
    const float* w1 = (const float*)d_in[2];
    const float* w2 = (const float*)d_in[3];
    const float* w3 = (const float*)d_in[4];
    float* out = (float*)d_out;

    char* ws = (char*)d_ws;
    int*   cnt    = (int*)(ws + 0);
    int*   cnt2   = (int*)(ws + 32);
    int*   off    = (int*)(ws + 64);
    int*   topi   = (int*)(ws + 256);
    float* topw   = (float*)(ws + 256 + 32768);
    int*   rowtok = (int*)(ws + 256 + 65536);
    float* rowwgt = (float*)(ws + 256 + 98304);
    unsigned short* Hbuf = (unsigned short*)(ws + (1 << 20));  // 2*NTOK x EXP bf16 = 64 MB

    hipMemsetAsync(ws, 0, 256, stream);
    hipMemsetAsync(d_out, 0, (size_t)out_size * sizeof(float), stream);

    gate_kernel<<<NTOK / 4, 256, 0, stream>>>(x, gw, topi, topw, cnt);
    offset_kernel<<<1, 64, 0, stream>>>(cnt, off, cnt2);
    fill_kernel<<<NTOK / 256, 256, 0, stream>>>(topi, topw, off, cnt2, rowtok, rowwgt);

    dim3 g1(NTOK / BM1, EXP / BN1, NE);
    gemm1_kernel<<<g1, 256, 0, stream>>>(x, w1, w3, rowtok, off, cnt, Hbuf);

    dim3 g2(NTOK / BM2, HID / BN2, NE);
    gemm2_kernel<<<g2, 256, 0, stream>>>(Hbuf, w2, rowtok, rowwgt, off, cnt, out);
}